// Round 1
// baseline (3778.836 us; speedup 1.0000x reference)
//
#include <hip/hip_runtime.h>
#include <hip/hip_bf16.h>

// Mamba mixer forward, fp32 throughout (round 1: correctness baseline).
// B=2, L=1024, D_MODEL=2048, D_INNER=4096, D_STATE=16, D_CONV=4, DT_RANK=128.

#define BATCH 2
#define SEQ 1024
#define DMODEL 2048
#define DINNER 4096
#define DSTATE 16
#define DTRANK 128
#define ROWS (BATCH * SEQ)          // 2048

#define BM 64
#define BN 64
#define BK 16

// Generic C = A @ B^T, A: M x K row-major (lda), B: N x K row-major (ldb).
// EPI 0: none; EPI 1: softplus(acc + bias[n]).
template <int EPI>
__global__ __launch_bounds__(256) void gemm_bt(
    const float* __restrict__ A, int lda,
    const float* __restrict__ B, int ldb,
    const float* __restrict__ bias,
    float* __restrict__ C, int ldc,
    int N, int K) {
  __shared__ float As[BK][BM + 1];
  __shared__ float Bs[BK][BN + 1];
  const int tid = threadIdx.x;
  const int tx = tid & 15;
  const int ty = tid >> 4;
  const int m0 = blockIdx.x * BM;
  const int n0 = blockIdx.y * BN;
  const int krow = tid & 15;   // k within tile for staging
  const int mrow = tid >> 4;   // row base for staging (step 16)

  float acc[4][4] = {};

  for (int k0 = 0; k0 < K; k0 += BK) {
#pragma unroll
    for (int i = 0; i < 4; i++) {
      int m = mrow + 16 * i;
      As[krow][m] = A[(size_t)(m0 + m) * lda + k0 + krow];
    }
#pragma unroll
    for (int i = 0; i < 4; i++) {
      int n = mrow + 16 * i;
      float v = 0.f;
      if (n0 + n < N) v = B[(size_t)(n0 + n) * ldb + k0 + krow];
      Bs[krow][n] = v;
    }
    __syncthreads();
#pragma unroll
    for (int k = 0; k < BK; k++) {
      float a[4], b[4];
#pragma unroll
      for (int i = 0; i < 4; i++) a[i] = As[k][ty * 4 + i];
#pragma unroll
      for (int j = 0; j < 4; j++) b[j] = Bs[k][tx * 4 + j];
#pragma unroll
      for (int i = 0; i < 4; i++)
#pragma unroll
        for (int j = 0; j < 4; j++) acc[i][j] += a[i] * b[j];
    }
    __syncthreads();
  }

#pragma unroll
  for (int i = 0; i < 4; i++) {
    int m = m0 + ty * 4 + i;
#pragma unroll
    for (int j = 0; j < 4; j++) {
      int n = n0 + tx * 4 + j;
      if (n < N) {
        float v = acc[i][j];
        if (EPI == 1) {
          v += bias[n];
          v = (v > 20.f) ? v : log1pf(__expf(v));  // softplus
        }
        C[(size_t)m * ldc + n] = v;
      }
    }
  }
}

// Causal depthwise conv (D_CONV=4) + SiLU over x half of xz.
__global__ __launch_bounds__(256) void conv_silu(
    const float* __restrict__ xz, const float* __restrict__ cw,
    const float* __restrict__ cb, float* __restrict__ xs) {
  int idx = blockIdx.x * 256 + threadIdx.x;  // over B*L*DINNER
  if (idx >= ROWS * DINNER) return;
  int d = idx & (DINNER - 1);
  int bt = idx >> 12;            // b*L + t
  int t = bt & (SEQ - 1);
  float acc = cb[d];
#pragma unroll
  for (int k = 0; k < 4; k++) {
    int tt = t - 3 + k;
    if (tt >= 0) acc += cw[d * 4 + k] * xz[(size_t)(bt - 3 + k) * (2 * DINNER) + d];
  }
  float s = acc / (1.f + __expf(-acc));  // silu
  xs[idx] = s;
}

// Selective scan: one lane per (b, d, n). 16-lane shfl_xor reduction gives
// y_t; lane n==0 applies skip + gate and writes in-place into the delta
// buffer (read of delta[t] precedes write within the iteration).
__global__ __launch_bounds__(256) void scan_kernel(
    const float* __restrict__ xz, const float* __restrict__ xs,
    const float* __restrict__ xdbl, float* __restrict__ delta_y,
    const float* __restrict__ A_log, const float* __restrict__ D_skip) {
  int tid = blockIdx.x * 256 + threadIdx.x;  // 131072 total
  int n = tid & 15;
  int ch = tid >> 4;       // 0..8191
  int d = ch & (DINNER - 1);
  int b = ch >> 12;

  float Adn = -__expf(A_log[d * DSTATE + n]);   // A = -exp(A_log)
  float Dd = D_skip[d];
  float h = 0.f;

  float* dl = delta_y + (size_t)b * SEQ * DINNER + d;
  const float* us = xs + (size_t)b * SEQ * DINNER + d;
  const float* zb = xz + (size_t)b * SEQ * (2 * DINNER) + DINNER + d;
  const float* bc = xdbl + (size_t)b * SEQ * (DTRANK + 2 * DSTATE);

  for (int t = 0; t < SEQ; t++) {
    float delta = dl[(size_t)t * DINNER];
    float u = us[(size_t)t * DINNER];
    float Bv = bc[t * (DTRANK + 2 * DSTATE) + DTRANK + n];
    float Cv = bc[t * (DTRANK + 2 * DSTATE) + DTRANK + DSTATE + n];
    float dA = __expf(delta * Adn);
    h = dA * h + (delta * u) * Bv;
    float v = h * Cv;
    v += __shfl_xor(v, 1, 64);
    v += __shfl_xor(v, 2, 64);
    v += __shfl_xor(v, 4, 64);
    v += __shfl_xor(v, 8, 64);
    if (n == 0) {
      float z = zb[(size_t)t * (2 * DINNER)];
      float sz = z / (1.f + __expf(-z));
      float g = (v + Dd * u) * sz;
      dl[(size_t)t * DINNER] = g;
    }
  }
}

extern "C" void kernel_launch(void* const* d_in, const int* in_sizes, int n_in,
                              void* d_out, int out_size, void* d_ws, size_t ws_size,
                              hipStream_t stream) {
  const float* hidden = (const float*)d_in[0];   // (B, L, DMODEL)
  const float* W_in   = (const float*)d_in[1];   // (2*Di, DMODEL)
  const float* conv_w = (const float*)d_in[2];   // (Di, 4)
  const float* conv_b = (const float*)d_in[3];   // (Di,)
  const float* W_x    = (const float*)d_in[4];   // (160, Di)
  const float* W_dt   = (const float*)d_in[5];   // (Di, 128)
  const float* b_dt   = (const float*)d_in[6];   // (Di,)
  const float* A_log  = (const float*)d_in[7];   // (Di, 16)
  const float* D_skip = (const float*)d_in[8];   // (Di,)
  const float* W_out  = (const float*)d_in[9];   // (DMODEL, Di)
  float* out = (float*)d_out;

  float* ws   = (float*)d_ws;
  float* xz   = ws;                               // ROWS * 2*Di   = 16,777,216
  float* xs   = xz + (size_t)ROWS * 2 * DINNER;   // ROWS * Di     =  8,388,608
  float* xdbl = xs + (size_t)ROWS * DINNER;       // ROWS * 160    =    327,680
  float* delta = xdbl + (size_t)ROWS * 160;       // ROWS * Di     =  8,388,608

  dim3 blk(256);

  // xz = hidden @ W_in^T : M=2048, K=2048, N=8192
  gemm_bt<0><<<dim3(ROWS / BM, 2 * DINNER / BN), blk, 0, stream>>>(
      hidden, DMODEL, W_in, DMODEL, nullptr, xz, 2 * DINNER, 2 * DINNER, DMODEL);

  // causal conv + silu -> xs
  conv_silu<<<(ROWS * DINNER + 255) / 256, blk, 0, stream>>>(xz, conv_w, conv_b, xs);

  // x_dbl = xs @ W_x^T : M=2048, K=4096, N=160
  gemm_bt<0><<<dim3(ROWS / BM, (160 + BN - 1) / BN), blk, 0, stream>>>(
      xs, DINNER, W_x, DINNER, nullptr, xdbl, 160, 160, DINNER);

  // delta = softplus(x_dbl[:, :128] @ W_dt^T + b_dt) : M=2048, K=128, N=4096
  gemm_bt<1><<<dim3(ROWS / BM, DINNER / BN), blk, 0, stream>>>(
      xdbl, 160, W_dt, DTRANK, b_dt, delta, DINNER, DINNER, DTRANK);

  // selective scan + skip + gate, in-place into delta buffer
  scan_kernel<<<(BATCH * DINNER * DSTATE) / 256, blk, 0, stream>>>(
      xz, xs, xdbl, delta, A_log, D_skip);

  // out = gated @ W_out^T : M=2048, K=4096, N=2048
  gemm_bt<0><<<dim3(ROWS / BM, DMODEL / BN), blk, 0, stream>>>(
      delta, DINNER, W_out, DINNER, nullptr, out, DMODEL, DMODEL, DINNER);
}

// Round 2
// 2428.751 us; speedup vs baseline: 1.5559x; 1.5559x over previous
//
#include <hip/hip_runtime.h>
#include <hip/hip_bf16.h>

// Mamba mixer forward, fp32. Round 2: register-blocked GEMM (8x8 micro-tiles),
// split-K for the skinny x_dbl GEMM.
// B=2, L=1024, D_MODEL=2048, D_INNER=4096, D_STATE=16, D_CONV=4, DT_RANK=128.

#define BATCH 2
#define SEQ 1024
#define DMODEL 2048
#define DINNER 4096
#define DSTATE 16
#define DTRANK 128
#define ROWS (BATCH * SEQ)          // 2048
#define XDBL_N (DTRANK + 2 * DSTATE)  // 160

// ---------------------------------------------------------------------------
// Tiled GEMM: C = A @ B^T.  A: M x K row-major (lda), B: N x K row-major (ldb).
// Tile = (64*GM) x (64*GN), BK=8, 256 threads, micro-tile (4*GM) x (4*GN) as
// GMxGN groups of 4x4 float4 fragments (contiguous -> ds_read_b128, <=2-way
// bank aliasing which is free on gfx950).
// EPI 0: none; EPI 1: softplus(acc + bias[n]).
// Split-K: blockIdx.z selects a K-slice of length kslice_len; output written
// at C + z*slice_stride. Non-split: gridDim.z=1, slice_stride=0, kslice_len=K.
// M must be a multiple of 64*GM (true for all call sites: M=2048).
// N guarded (handles N=160). K slice length must be a multiple of 8.
// ---------------------------------------------------------------------------
template <int GM, int GN, int EPI>
__global__ __launch_bounds__(256) void gemm_tile(
    const float* __restrict__ A, int lda,
    const float* __restrict__ B, int ldb,
    const float* __restrict__ bias,
    float* __restrict__ C, int ldc,
    int N, int kslice_len, size_t slice_stride) {
  constexpr int BM = 64 * GM;
  constexpr int BN = 64 * GN;
  __shared__ float As[8][BM];   // k-major
  __shared__ float Bs[8][BN];

  const int tid = threadIdx.x;
  const int tx = tid & 15;      // n-group index
  const int ty = tid >> 4;      // m-group index
  const int m0 = blockIdx.x * BM;
  const int n0 = blockIdx.y * BN;
  const int kbase = blockIdx.z * kslice_len;

  // staging: one float4 (4 consecutive k) per active thread
  const int srow = tid >> 1;           // row within tile
  const int skk = (tid & 1) * 4;       // k offset within BK
  const bool a_act = (tid < BM * 2);
  const bool b_act = (tid < BN * 2);
  const bool b_in = b_act && (n0 + srow < N);

  const float* Aptr = A + (size_t)(m0 + srow) * lda + kbase + skk;
  const float* Bptr = B + (size_t)(n0 + srow) * ldb + kbase + skk;

  float4 pa = make_float4(0.f, 0.f, 0.f, 0.f);
  float4 pb = make_float4(0.f, 0.f, 0.f, 0.f);
  if (a_act) pa = *(const float4*)Aptr;
  if (b_in)  pb = *(const float4*)Bptr;

  float acc[GM][GN][4][4] = {};

  for (int kt = 0; kt < kslice_len; kt += 8) {
    __syncthreads();   // previous compute done; LDS free
    if (a_act) {
      As[skk + 0][srow] = pa.x;
      As[skk + 1][srow] = pa.y;
      As[skk + 2][srow] = pa.z;
      As[skk + 3][srow] = pa.w;
    }
    if (b_act) {
      Bs[skk + 0][srow] = pb.x;
      Bs[skk + 1][srow] = pb.y;
      Bs[skk + 2][srow] = pb.z;
      Bs[skk + 3][srow] = pb.w;
    }
    __syncthreads();

    // prefetch next K-tile while computing this one
    if (kt + 8 < kslice_len) {
      if (a_act) pa = *(const float4*)(Aptr + kt + 8);
      if (b_in)  pb = *(const float4*)(Bptr + kt + 8);
    }

#pragma unroll
    for (int k = 0; k < 8; k++) {
      float a[GM][4], b[GN][4];
#pragma unroll
      for (int g = 0; g < GM; g++)
        *(float4*)&a[g][0] = *(const float4*)&As[k][g * 64 + ty * 4];
#pragma unroll
      for (int g = 0; g < GN; g++)
        *(float4*)&b[g][0] = *(const float4*)&Bs[k][g * 64 + tx * 4];
#pragma unroll
      for (int gm = 0; gm < GM; gm++)
#pragma unroll
        for (int i = 0; i < 4; i++)
#pragma unroll
          for (int gn = 0; gn < GN; gn++)
#pragma unroll
            for (int j = 0; j < 4; j++)
              acc[gm][gn][i][j] += a[gm][i] * b[gn][j];
    }
  }

  float* Cs = C + (size_t)blockIdx.z * slice_stride;
#pragma unroll
  for (int gm = 0; gm < GM; gm++) {
#pragma unroll
    for (int i = 0; i < 4; i++) {
      int m = m0 + gm * 64 + ty * 4 + i;
#pragma unroll
      for (int gn = 0; gn < GN; gn++) {
        int n = n0 + gn * 64 + tx * 4;
        if (n < N) {   // N is always a multiple of 4; float4 store safe
          float4 v;
          v.x = acc[gm][gn][i][0];
          v.y = acc[gm][gn][i][1];
          v.z = acc[gm][gn][i][2];
          v.w = acc[gm][gn][i][3];
          if (EPI == 1) {
            v.x += bias[n + 0];
            v.y += bias[n + 1];
            v.z += bias[n + 2];
            v.w += bias[n + 3];
            v.x = (v.x > 20.f) ? v.x : log1pf(__expf(v.x));
            v.y = (v.y > 20.f) ? v.y : log1pf(__expf(v.y));
            v.z = (v.z > 20.f) ? v.z : log1pf(__expf(v.z));
            v.w = (v.w > 20.f) ? v.w : log1pf(__expf(v.w));
          }
          *(float4*)&Cs[(size_t)m * ldc + n] = v;
        }
      }
    }
  }
}

// Sum 4 split-K partial buffers into xdbl.
__global__ __launch_bounds__(256) void reduce4(
    const float* __restrict__ partials, float* __restrict__ outb, int n) {
  int i = blockIdx.x * 256 + threadIdx.x;
  if (i >= n) return;
  outb[i] = partials[i] + partials[i + n] + partials[i + 2 * n] + partials[i + 3 * n];
}

// Causal depthwise conv (D_CONV=4) + SiLU over x half of xz.
__global__ __launch_bounds__(256) void conv_silu(
    const float* __restrict__ xz, const float* __restrict__ cw,
    const float* __restrict__ cb, float* __restrict__ xs) {
  int idx = blockIdx.x * 256 + threadIdx.x;  // over B*L*DINNER
  if (idx >= ROWS * DINNER) return;
  int d = idx & (DINNER - 1);
  int bt = idx >> 12;            // b*L + t
  int t = bt & (SEQ - 1);
  float acc = cb[d];
#pragma unroll
  for (int k = 0; k < 4; k++) {
    int tt = t - 3 + k;
    if (tt >= 0) acc += cw[d * 4 + k] * xz[(size_t)(bt - 3 + k) * (2 * DINNER) + d];
  }
  xs[idx] = acc / (1.f + __expf(-acc));  // silu
}

// Selective scan: one lane per (b, d, n). 16-lane shfl_xor reduction gives
// y_t; lane n==0 applies skip + gate and writes in-place into delta buffer.
__global__ __launch_bounds__(256) void scan_kernel(
    const float* __restrict__ xz, const float* __restrict__ xs,
    const float* __restrict__ xdbl, float* __restrict__ delta_y,
    const float* __restrict__ A_log, const float* __restrict__ D_skip) {
  int tid = blockIdx.x * 256 + threadIdx.x;  // 131072 total
  int n = tid & 15;
  int ch = tid >> 4;       // 0..8191
  int d = ch & (DINNER - 1);
  int b = ch >> 12;

  float Adn = -__expf(A_log[d * DSTATE + n]);   // A = -exp(A_log)
  float Dd = D_skip[d];
  float h = 0.f;

  float* dl = delta_y + (size_t)b * SEQ * DINNER + d;
  const float* us = xs + (size_t)b * SEQ * DINNER + d;
  const float* zb = xz + (size_t)b * SEQ * (2 * DINNER) + DINNER + d;
  const float* bc = xdbl + (size_t)b * SEQ * XDBL_N;

  for (int t = 0; t < SEQ; t++) {
    float delta = dl[(size_t)t * DINNER];
    float u = us[(size_t)t * DINNER];
    float Bv = bc[t * XDBL_N + DTRANK + n];
    float Cv = bc[t * XDBL_N + DTRANK + DSTATE + n];
    float dA = __expf(delta * Adn);
    h = dA * h + (delta * u) * Bv;
    float v = h * Cv;
    v += __shfl_xor(v, 1, 64);
    v += __shfl_xor(v, 2, 64);
    v += __shfl_xor(v, 4, 64);
    v += __shfl_xor(v, 8, 64);
    if (n == 0) {
      float z = zb[(size_t)t * (2 * DINNER)];
      float sz = z / (1.f + __expf(-z));
      dl[(size_t)t * DINNER] = (v + Dd * u) * sz;
    }
  }
}

extern "C" void kernel_launch(void* const* d_in, const int* in_sizes, int n_in,
                              void* d_out, int out_size, void* d_ws, size_t ws_size,
                              hipStream_t stream) {
  const float* hidden = (const float*)d_in[0];   // (B, L, DMODEL)
  const float* W_in   = (const float*)d_in[1];   // (2*Di, DMODEL)
  const float* conv_w = (const float*)d_in[2];   // (Di, 4)
  const float* conv_b = (const float*)d_in[3];   // (Di,)
  const float* W_x    = (const float*)d_in[4];   // (160, Di)
  const float* W_dt   = (const float*)d_in[5];   // (Di, 128)
  const float* b_dt   = (const float*)d_in[6];   // (Di,)
  const float* A_log  = (const float*)d_in[7];   // (Di, 16)
  const float* D_skip = (const float*)d_in[8];   // (Di,)
  const float* W_out  = (const float*)d_in[9];   // (DMODEL, Di)
  float* out = (float*)d_out;

  float* ws    = (float*)d_ws;
  float* xz    = ws;                               // ROWS*2*Di = 16,777,216 f
  float* xs    = xz + (size_t)ROWS * 2 * DINNER;   // ROWS*Di   =  8,388,608 f
  float* xdbl  = xs + (size_t)ROWS * DINNER;       // ROWS*160  =    327,680 f
  float* delta = xdbl + (size_t)ROWS * XDBL_N;     // ROWS*Di   =  8,388,608 f
  // split-K partials for GEMM2 alias the delta buffer (delta is written later,
  // by GEMM3): 4 * 327,680 = 1,310,720 floats <= 8,388,608.
  float* partials = delta;

  dim3 blk(256);

  // GEMM1: xz = hidden @ W_in^T : M=2048, N=8192, K=2048. 128x128 tiles.
  gemm_tile<2, 2, 0><<<dim3(ROWS / 128, 2 * DINNER / 128, 1), blk, 0, stream>>>(
      hidden, DMODEL, W_in, DMODEL, nullptr, xz, 2 * DINNER,
      2 * DINNER, DMODEL, 0);

  // causal conv + silu -> xs
  conv_silu<<<(ROWS * DINNER + 255) / 256, blk, 0, stream>>>(xz, conv_w, conv_b, xs);

  // GEMM2: x_dbl = xs @ W_x^T : M=2048, N=160, K=4096. 64x64 tiles, split-K=4.
  gemm_tile<1, 1, 0><<<dim3(ROWS / 64, 3, 4), blk, 0, stream>>>(
      xs, DINNER, W_x, DINNER, nullptr, partials, XDBL_N,
      XDBL_N, DINNER / 4, (size_t)ROWS * XDBL_N);
  reduce4<<<(ROWS * XDBL_N + 255) / 256, blk, 0, stream>>>(
      partials, xdbl, ROWS * XDBL_N);

  // GEMM3: delta = softplus(x_dbl[:, :128] @ W_dt^T + b_dt) : M=2048, N=4096, K=128.
  gemm_tile<2, 2, 1><<<dim3(ROWS / 128, DINNER / 128, 1), blk, 0, stream>>>(
      xdbl, XDBL_N, W_dt, DTRANK, b_dt, delta, DINNER,
      DINNER, DTRANK, 0);

  // selective scan + skip + gate, in-place into delta buffer
  scan_kernel<<<(BATCH * DINNER * DSTATE) / 256, blk, 0, stream>>>(
      xz, xs, xdbl, delta, A_log, D_skip);

  // GEMM4: out = gated @ W_out^T : M=2048, N=2048, K=4096. 64x128 tiles (2 blk/CU).
  gemm_tile<1, 2, 0><<<dim3(ROWS / 64, DMODEL / 128, 1), blk, 0, stream>>>(
      delta, DINNER, W_out, DINNER, nullptr, out, DMODEL,
      DMODEL, DINNER, 0);
}

// Round 3
// 1401.782 us; speedup vs baseline: 2.6957x; 1.7326x over previous
//
#include <hip/hip_runtime.h>
#include <hip/hip_bf16.h>

// Mamba mixer forward. Round 3: GEMM1/GEMM4 on bf16 MFMA with hi/lo split
// (3-MFMA scheme, fp32-equivalent ~2^-18 rel error), global_load_lds width-16
// staging with XOR-swizzled LDS layout (conflict-free ds_read_b128).
// B=2, L=1024, D_MODEL=2048, D_INNER=4096, D_STATE=16, D_CONV=4, DT_RANK=128.

#define BATCH 2
#define SEQ 1024
#define DMODEL 2048
#define DINNER 4096
#define DSTATE 16
#define DTRANK 128
#define ROWS (BATCH * SEQ)            // 2048
#define XDBL_N (DTRANK + 2 * DSTATE)  // 160

typedef unsigned short ushort_t;
typedef __attribute__((ext_vector_type(8))) short short8;
typedef __attribute__((ext_vector_type(4))) float f32x4;

// ---------------------------------------------------------------------------
// bf16 split helpers
// ---------------------------------------------------------------------------
__device__ __forceinline__ ushort_t bf16_rne(float f) {
  unsigned u = __float_as_uint(f);
  return (ushort_t)((u + 0x7FFFu + ((u >> 16) & 1u)) >> 16);
}
__device__ __forceinline__ float bf16_to_f32(ushort_t h) {
  return __uint_as_float(((unsigned)h) << 16);
}

// x -> (hi, lo) bf16 pair. n4 = n/4.
__global__ __launch_bounds__(256) void split_bf16(
    const float* __restrict__ x, ushort_t* __restrict__ h,
    ushort_t* __restrict__ l, int n4) {
  int i = blockIdx.x * 256 + threadIdx.x;
  if (i >= n4) return;
  float4 v = ((const float4*)x)[i];
  ushort4 hh, ll;
  hh.x = bf16_rne(v.x); ll.x = bf16_rne(v.x - bf16_to_f32(hh.x));
  hh.y = bf16_rne(v.y); ll.y = bf16_rne(v.y - bf16_to_f32(hh.y));
  hh.z = bf16_rne(v.z); ll.z = bf16_rne(v.z - bf16_to_f32(hh.z));
  hh.w = bf16_rne(v.w); ll.w = bf16_rne(v.w - bf16_to_f32(hh.w));
  ((ushort4*)h)[i] = hh;
  ((ushort4*)l)[i] = ll;
}

// ---------------------------------------------------------------------------
// Split-precision bf16 MFMA GEMM: C = X @ W^T, fp32 out.
// X: M x K (hi/lo bf16 arrays), W: N x K (hi/lo). TM x TN tile, 256 thr
// (4 waves, 2x2), BK=64. Wave w stages array w via global_load_lds(16B).
// LDS layout per array: slot16(m, c) = m*8 + (c ^ (m&7)) (16B units), which is
// lane-linear for the DMA and gives <=2-way bank aliasing on fragment reads.
// M % TM == 0, N % TN == 0, K % 64 == 0 (true at both call sites).
// ---------------------------------------------------------------------------
template <int TM, int TN>
__global__ __launch_bounds__(256, 2) void gemm_mfma(
    const ushort_t* __restrict__ Xh, const ushort_t* __restrict__ Xl,
    const ushort_t* __restrict__ Wh, const ushort_t* __restrict__ Wl,
    float* __restrict__ C, int ldc, int K) {
  constexpr int MI = TM / 32;   // MFMA tiles per wave in m
  constexpr int NI = TN / 32;   // MFMA tiles per wave in n
  __shared__ __attribute__((aligned(16))) ushort_t lds[(2 * TM + 2 * TN) * 64];
  ushort_t* Ahs = lds;
  ushort_t* Als = Ahs + TM * 64;
  ushort_t* Bhs = Als + TM * 64;
  ushort_t* Bls = Bhs + TN * 64;

  const int tid = threadIdx.x;
  const int lane = tid & 63;
  const int w = tid >> 6;
  const int wm = w & 1, wn = w >> 1;
  const int m0 = blockIdx.x * TM;
  const int n0 = blockIdx.y * TN;

  // staging: wave w owns one array
  const ushort_t* sbase = (w == 0) ? Xh : (w == 1) ? Xl : (w == 2) ? Wh : Wl;
  ushort_t* dbase = (w == 0) ? Ahs : (w == 1) ? Als : (w == 2) ? Bhs : Bls;
  const int srow0 = (w < 2) ? m0 : n0;
  const int ninstr = ((w < 2) ? TM : TN) / 8;   // 8 rows per instruction
  const int lrow = lane >> 3;                   // 0..7
  const int csw = (lane & 7) ^ lrow;            // swizzled chunk for this lane
  const ushort_t* sptr = sbase + (size_t)(srow0 + lrow) * K + csw * 8;

  // fragment read bases (short units). addr16(m,c) = m*8 + (c ^ (m&7)).
  const int quad = lane >> 4;
  const int l15 = lane & 15;
  const int x0 = quad ^ (lane & 7);
  const int baseA = (wm * (TM / 2) + l15) * 64;   // m*8 addr16 -> *8 shorts
  const int baseB = (wn * (TN / 2) + l15) * 64;

  f32x4 acc[MI][NI] = {};

  for (int kt = 0; kt < K; kt += 64) {
    const ushort_t* sp = sptr + kt;
    ushort_t* dp = dbase;
    for (int i = 0; i < ninstr; i++) {
      __builtin_amdgcn_global_load_lds(
          (const __attribute__((address_space(1))) unsigned int*)sp,
          (__attribute__((address_space(3))) unsigned int*)dp, 16, 0, 0);
      sp += (size_t)8 * K;
      dp += 512;   // 64 lanes * 8 shorts
    }
    __syncthreads();   // drains vmcnt before barrier -> tile ready

#pragma unroll
    for (int ks = 0; ks < 2; ks++) {
      const int xo = (x0 ^ (ks * 4)) * 8;
      short8 ah[MI], al[MI], bh[NI], bl[NI];
#pragma unroll
      for (int mi = 0; mi < MI; mi++) {
        ah[mi] = *(const short8*)&Ahs[baseA + mi * 1024 + xo];
        al[mi] = *(const short8*)&Als[baseA + mi * 1024 + xo];
      }
#pragma unroll
      for (int ni = 0; ni < NI; ni++) {
        bh[ni] = *(const short8*)&Bhs[baseB + ni * 1024 + xo];
        bl[ni] = *(const short8*)&Bls[baseB + ni * 1024 + xo];
      }
#pragma unroll
      for (int mi = 0; mi < MI; mi++)
#pragma unroll
        for (int ni = 0; ni < NI; ni++) {
          f32x4 a = acc[mi][ni];
          a = __builtin_amdgcn_mfma_f32_16x16x32_bf16(al[mi], bh[ni], a, 0, 0, 0);
          a = __builtin_amdgcn_mfma_f32_16x16x32_bf16(ah[mi], bl[ni], a, 0, 0, 0);
          a = __builtin_amdgcn_mfma_f32_16x16x32_bf16(ah[mi], bh[ni], a, 0, 0, 0);
          acc[mi][ni] = a;
        }
    }
    __syncthreads();
  }

  // C/D layout: col = lane&15, row = quad*4 + reg
#pragma unroll
  for (int mi = 0; mi < MI; mi++)
#pragma unroll
    for (int ni = 0; ni < NI; ni++) {
      int row = m0 + wm * (TM / 2) + mi * 16 + quad * 4;
      int col = n0 + wn * (TN / 2) + ni * 16 + l15;
#pragma unroll
      for (int r = 0; r < 4; r++)
        C[(size_t)(row + r) * ldc + col] = acc[mi][ni][r];
    }
}

// ---------------------------------------------------------------------------
// fp32 register-blocked GEMM (round-2 kernel) — kept for the small GEMMs.
// ---------------------------------------------------------------------------
template <int GM, int GN, int EPI>
__global__ __launch_bounds__(256) void gemm_tile(
    const float* __restrict__ A, int lda,
    const float* __restrict__ B, int ldb,
    const float* __restrict__ bias,
    float* __restrict__ C, int ldc,
    int N, int kslice_len, size_t slice_stride) {
  constexpr int BM = 64 * GM;
  constexpr int BN = 64 * GN;
  __shared__ float As[8][BM];
  __shared__ float Bs[8][BN];

  const int tid = threadIdx.x;
  const int tx = tid & 15;
  const int ty = tid >> 4;
  const int m0 = blockIdx.x * BM;
  const int n0 = blockIdx.y * BN;
  const int kbase = blockIdx.z * kslice_len;

  const int srow = tid >> 1;
  const int skk = (tid & 1) * 4;
  const bool a_act = (tid < BM * 2);
  const bool b_act = (tid < BN * 2);
  const bool b_in = b_act && (n0 + srow < N);

  const float* Aptr = A + (size_t)(m0 + srow) * lda + kbase + skk;
  const float* Bptr = B + (size_t)(n0 + srow) * ldb + kbase + skk;

  float4 pa = make_float4(0.f, 0.f, 0.f, 0.f);
  float4 pb = make_float4(0.f, 0.f, 0.f, 0.f);
  if (a_act) pa = *(const float4*)Aptr;
  if (b_in)  pb = *(const float4*)Bptr;

  float acc[GM][GN][4][4] = {};

  for (int kt = 0; kt < kslice_len; kt += 8) {
    __syncthreads();
    if (a_act) {
      As[skk + 0][srow] = pa.x; As[skk + 1][srow] = pa.y;
      As[skk + 2][srow] = pa.z; As[skk + 3][srow] = pa.w;
    }
    if (b_act) {
      Bs[skk + 0][srow] = pb.x; Bs[skk + 1][srow] = pb.y;
      Bs[skk + 2][srow] = pb.z; Bs[skk + 3][srow] = pb.w;
    }
    __syncthreads();
    if (kt + 8 < kslice_len) {
      if (a_act) pa = *(const float4*)(Aptr + kt + 8);
      if (b_in)  pb = *(const float4*)(Bptr + kt + 8);
    }
#pragma unroll
    for (int k = 0; k < 8; k++) {
      float a[GM][4], b[GN][4];
#pragma unroll
      for (int g = 0; g < GM; g++)
        *(float4*)&a[g][0] = *(const float4*)&As[k][g * 64 + ty * 4];
#pragma unroll
      for (int g = 0; g < GN; g++)
        *(float4*)&b[g][0] = *(const float4*)&Bs[k][g * 64 + tx * 4];
#pragma unroll
      for (int gm = 0; gm < GM; gm++)
#pragma unroll
        for (int i = 0; i < 4; i++)
#pragma unroll
          for (int gn = 0; gn < GN; gn++)
#pragma unroll
            for (int j = 0; j < 4; j++)
              acc[gm][gn][i][j] += a[gm][i] * b[gn][j];
    }
  }

  float* Cs = C + (size_t)blockIdx.z * slice_stride;
#pragma unroll
  for (int gm = 0; gm < GM; gm++) {
#pragma unroll
    for (int i = 0; i < 4; i++) {
      int m = m0 + gm * 64 + ty * 4 + i;
#pragma unroll
      for (int gn = 0; gn < GN; gn++) {
        int n = n0 + gn * 64 + tx * 4;
        if (n < N) {
          float4 v;
          v.x = acc[gm][gn][i][0]; v.y = acc[gm][gn][i][1];
          v.z = acc[gm][gn][i][2]; v.w = acc[gm][gn][i][3];
          if (EPI == 1) {
            v.x += bias[n + 0]; v.y += bias[n + 1];
            v.z += bias[n + 2]; v.w += bias[n + 3];
            v.x = (v.x > 20.f) ? v.x : log1pf(__expf(v.x));
            v.y = (v.y > 20.f) ? v.y : log1pf(__expf(v.y));
            v.z = (v.z > 20.f) ? v.z : log1pf(__expf(v.z));
            v.w = (v.w > 20.f) ? v.w : log1pf(__expf(v.w));
          }
          *(float4*)&Cs[(size_t)m * ldc + n] = v;
        }
      }
    }
  }
}

__global__ __launch_bounds__(256) void reduce4(
    const float* __restrict__ partials, float* __restrict__ outb, int n) {
  int i = blockIdx.x * 256 + threadIdx.x;
  if (i >= n) return;
  outb[i] = partials[i] + partials[i + n] + partials[i + 2 * n] + partials[i + 3 * n];
}

__global__ __launch_bounds__(256) void conv_silu(
    const float* __restrict__ xz, const float* __restrict__ cw,
    const float* __restrict__ cb, float* __restrict__ xs) {
  int idx = blockIdx.x * 256 + threadIdx.x;
  if (idx >= ROWS * DINNER) return;
  int d = idx & (DINNER - 1);
  int bt = idx >> 12;
  int t = bt & (SEQ - 1);
  float acc = cb[d];
#pragma unroll
  for (int k = 0; k < 4; k++) {
    int tt = t - 3 + k;
    if (tt >= 0) acc += cw[d * 4 + k] * xz[(size_t)(bt - 3 + k) * (2 * DINNER) + d];
  }
  xs[idx] = acc / (1.f + __expf(-acc));
}

__global__ __launch_bounds__(256) void scan_kernel(
    const float* __restrict__ xz, const float* __restrict__ xs,
    const float* __restrict__ xdbl, float* __restrict__ delta_y,
    const float* __restrict__ A_log, const float* __restrict__ D_skip) {
  int tid = blockIdx.x * 256 + threadIdx.x;
  int n = tid & 15;
  int ch = tid >> 4;
  int d = ch & (DINNER - 1);
  int b = ch >> 12;

  float Adn = -__expf(A_log[d * DSTATE + n]);
  float Dd = D_skip[d];
  float h = 0.f;

  float* dl = delta_y + (size_t)b * SEQ * DINNER + d;
  const float* us = xs + (size_t)b * SEQ * DINNER + d;
  const float* zb = xz + (size_t)b * SEQ * (2 * DINNER) + DINNER + d;
  const float* bc = xdbl + (size_t)b * SEQ * XDBL_N;

  for (int t = 0; t < SEQ; t++) {
    float delta = dl[(size_t)t * DINNER];
    float u = us[(size_t)t * DINNER];
    float Bv = bc[t * XDBL_N + DTRANK + n];
    float Cv = bc[t * XDBL_N + DTRANK + DSTATE + n];
    float dA = __expf(delta * Adn);
    h = dA * h + (delta * u) * Bv;
    float v = h * Cv;
    v += __shfl_xor(v, 1, 64);
    v += __shfl_xor(v, 2, 64);
    v += __shfl_xor(v, 4, 64);
    v += __shfl_xor(v, 8, 64);
    if (n == 0) {
      float z = zb[(size_t)t * (2 * DINNER)];
      float sz = z / (1.f + __expf(-z));
      dl[(size_t)t * DINNER] = (v + Dd * u) * sz;
    }
  }
}

extern "C" void kernel_launch(void* const* d_in, const int* in_sizes, int n_in,
                              void* d_out, int out_size, void* d_ws, size_t ws_size,
                              hipStream_t stream) {
  const float* hidden = (const float*)d_in[0];
  const float* W_in   = (const float*)d_in[1];
  const float* conv_w = (const float*)d_in[2];
  const float* conv_b = (const float*)d_in[3];
  const float* W_x    = (const float*)d_in[4];
  const float* W_dt   = (const float*)d_in[5];
  const float* b_dt   = (const float*)d_in[6];
  const float* A_log  = (const float*)d_in[7];
  const float* D_skip = (const float*)d_in[8];
  const float* W_out  = (const float*)d_in[9];
  float* out = (float*)d_out;

  float* ws    = (float*)d_ws;
  float* xz    = ws;                                 // 16,777,216 f
  float* xs    = xz + (size_t)ROWS * 2 * DINNER;     //  8,388,608 f
  float* xdbl  = xs + (size_t)ROWS * DINNER;         //    327,680 f
  float* delta = xdbl + (size_t)ROWS * XDBL_N;       //  8,388,608 f
  float* partials = delta;                           // GEMM2 scratch (pre-GEMM3)
  // bf16 split regions (ushort). Xh/Xl sized for the larger user (gated, 8.4M).
  ushort_t* Xh = (ushort_t*)(delta + (size_t)ROWS * DINNER);
  ushort_t* Xl = Xh + (size_t)ROWS * DINNER;         // 8,388,608 us each
  ushort_t* Wh = Xl + (size_t)ROWS * DINNER;         // 16,777,216 us each
  ushort_t* Wl = Wh + (size_t)2 * DINNER * DMODEL;
  // total ws: 135.5 MB f32 + 100.7 MB splits = 236 MB

  dim3 blk(256);

  // split hidden (2048x2048) and W_in (8192x2048)
  split_bf16<<<(ROWS * DMODEL / 4 + 255) / 256, blk, 0, stream>>>(
      hidden, Xh, Xl, ROWS * DMODEL / 4);
  split_bf16<<<(2 * DINNER * DMODEL / 4 + 255) / 256, blk, 0, stream>>>(
      W_in, Wh, Wl, 2 * DINNER * DMODEL / 4);

  // GEMM1 (MFMA): xz = hidden @ W_in^T : M=2048, N=8192, K=2048
  gemm_mfma<128, 128><<<dim3(ROWS / 128, 2 * DINNER / 128), blk, 0, stream>>>(
      Xh, Xl, Wh, Wl, xz, 2 * DINNER, DMODEL);

  conv_silu<<<(ROWS * DINNER + 255) / 256, blk, 0, stream>>>(xz, conv_w, conv_b, xs);

  // GEMM2 (fp32): x_dbl = xs @ W_x^T : M=2048, N=160, K=4096, split-K=4
  gemm_tile<1, 1, 0><<<dim3(ROWS / 64, 3, 4), blk, 0, stream>>>(
      xs, DINNER, W_x, DINNER, nullptr, partials, XDBL_N,
      XDBL_N, DINNER / 4, (size_t)ROWS * XDBL_N);
  reduce4<<<(ROWS * XDBL_N + 255) / 256, blk, 0, stream>>>(
      partials, xdbl, ROWS * XDBL_N);

  // GEMM3 (fp32): delta = softplus(x_dbl[:, :128] @ W_dt^T + b_dt)
  gemm_tile<2, 2, 1><<<dim3(ROWS / 128, DINNER / 128, 1), blk, 0, stream>>>(
      xdbl, XDBL_N, W_dt, DTRANK, b_dt, delta, DINNER,
      DINNER, DTRANK, 0);

  // selective scan + skip + gate, in-place into delta
  scan_kernel<<<(BATCH * DINNER * DSTATE) / 256, blk, 0, stream>>>(
      xz, xs, xdbl, delta, A_log, D_skip);

  // split gated (2048x4096) and W_out (2048x4096)
  split_bf16<<<(ROWS * DINNER / 4 + 255) / 256, blk, 0, stream>>>(
      delta, Xh, Xl, ROWS * DINNER / 4);
  split_bf16<<<(DMODEL * DINNER / 4 + 255) / 256, blk, 0, stream>>>(
      W_out, Wh, Wl, DMODEL * DINNER / 4);

  // GEMM4 (MFMA): out = gated @ W_out^T : M=2048, N=2048, K=4096
  gemm_mfma<128, 64><<<dim3(ROWS / 128, DMODEL / 64), blk, 0, stream>>>(
      Xh, Xl, Wh, Wl, out, DMODEL, DINNER);
}

// Round 4
// 751.251 us; speedup vs baseline: 5.0301x; 1.8659x over previous
//
#include <hip/hip_runtime.h>
#include <hip/hip_bf16.h>

// Mamba mixer forward. Round 4: chunked associative selective scan (3 passes,
// no per-step cross-lane reduction), bf16-split MFMA for GEMM1/GEMM4.
// B=2, L=1024, D_MODEL=2048, D_INNER=4096, D_STATE=16, D_CONV=4, DT_RANK=128.

#define BATCH 2
#define SEQ 1024
#define DMODEL 2048
#define DINNER 4096
#define DSTATE 16
#define DTRANK 128
#define ROWS (BATCH * SEQ)            // 2048
#define XDBL_N (DTRANK + 2 * DSTATE)  // 160
#define NCHUNK 64
#define CLEN (SEQ / NCHUNK)           // 16

typedef unsigned short ushort_t;
typedef __attribute__((ext_vector_type(8))) short short8;
typedef __attribute__((ext_vector_type(4))) float f32x4;

// ---------------------------------------------------------------------------
// bf16 split helpers
// ---------------------------------------------------------------------------
__device__ __forceinline__ ushort_t bf16_rne(float f) {
  unsigned u = __float_as_uint(f);
  return (ushort_t)((u + 0x7FFFu + ((u >> 16) & 1u)) >> 16);
}
__device__ __forceinline__ float bf16_to_f32(ushort_t h) {
  return __uint_as_float(((unsigned)h) << 16);
}

__global__ __launch_bounds__(256) void split_bf16(
    const float* __restrict__ x, ushort_t* __restrict__ h,
    ushort_t* __restrict__ l, int n4) {
  int i = blockIdx.x * 256 + threadIdx.x;
  if (i >= n4) return;
  float4 v = ((const float4*)x)[i];
  ushort4 hh, ll;
  hh.x = bf16_rne(v.x); ll.x = bf16_rne(v.x - bf16_to_f32(hh.x));
  hh.y = bf16_rne(v.y); ll.y = bf16_rne(v.y - bf16_to_f32(hh.y));
  hh.z = bf16_rne(v.z); ll.z = bf16_rne(v.z - bf16_to_f32(hh.z));
  hh.w = bf16_rne(v.w); ll.w = bf16_rne(v.w - bf16_to_f32(hh.w));
  ((ushort4*)h)[i] = hh;
  ((ushort4*)l)[i] = ll;
}

// ---------------------------------------------------------------------------
// Split-precision bf16 MFMA GEMM: C = X @ W^T, fp32 out. (round-3 kernel)
// ---------------------------------------------------------------------------
template <int TM, int TN>
__global__ __launch_bounds__(256, 2) void gemm_mfma(
    const ushort_t* __restrict__ Xh, const ushort_t* __restrict__ Xl,
    const ushort_t* __restrict__ Wh, const ushort_t* __restrict__ Wl,
    float* __restrict__ C, int ldc, int K) {
  constexpr int MI = TM / 32;
  constexpr int NI = TN / 32;
  __shared__ __attribute__((aligned(16))) ushort_t lds[(2 * TM + 2 * TN) * 64];
  ushort_t* Ahs = lds;
  ushort_t* Als = Ahs + TM * 64;
  ushort_t* Bhs = Als + TM * 64;
  ushort_t* Bls = Bhs + TN * 64;

  const int tid = threadIdx.x;
  const int lane = tid & 63;
  const int w = tid >> 6;
  const int wm = w & 1, wn = w >> 1;
  const int m0 = blockIdx.x * TM;
  const int n0 = blockIdx.y * TN;

  const ushort_t* sbase = (w == 0) ? Xh : (w == 1) ? Xl : (w == 2) ? Wh : Wl;
  ushort_t* dbase = (w == 0) ? Ahs : (w == 1) ? Als : (w == 2) ? Bhs : Bls;
  const int srow0 = (w < 2) ? m0 : n0;
  const int ninstr = ((w < 2) ? TM : TN) / 8;
  const int lrow = lane >> 3;
  const int csw = (lane & 7) ^ lrow;
  const ushort_t* sptr = sbase + (size_t)(srow0 + lrow) * K + csw * 8;

  const int quad = lane >> 4;
  const int l15 = lane & 15;
  const int x0 = quad ^ (lane & 7);
  const int baseA = (wm * (TM / 2) + l15) * 64;
  const int baseB = (wn * (TN / 2) + l15) * 64;

  f32x4 acc[MI][NI] = {};

  for (int kt = 0; kt < K; kt += 64) {
    const ushort_t* sp = sptr + kt;
    ushort_t* dp = dbase;
    for (int i = 0; i < ninstr; i++) {
      __builtin_amdgcn_global_load_lds(
          (const __attribute__((address_space(1))) unsigned int*)sp,
          (__attribute__((address_space(3))) unsigned int*)dp, 16, 0, 0);
      sp += (size_t)8 * K;
      dp += 512;
    }
    __syncthreads();

#pragma unroll
    for (int ks = 0; ks < 2; ks++) {
      const int xo = (x0 ^ (ks * 4)) * 8;
      short8 ah[MI], al[MI], bh[NI], bl[NI];
#pragma unroll
      for (int mi = 0; mi < MI; mi++) {
        ah[mi] = *(const short8*)&Ahs[baseA + mi * 1024 + xo];
        al[mi] = *(const short8*)&Als[baseA + mi * 1024 + xo];
      }
#pragma unroll
      for (int ni = 0; ni < NI; ni++) {
        bh[ni] = *(const short8*)&Bhs[baseB + ni * 1024 + xo];
        bl[ni] = *(const short8*)&Bls[baseB + ni * 1024 + xo];
      }
#pragma unroll
      for (int mi = 0; mi < MI; mi++)
#pragma unroll
        for (int ni = 0; ni < NI; ni++) {
          f32x4 a = acc[mi][ni];
          a = __builtin_amdgcn_mfma_f32_16x16x32_bf16(al[mi], bh[ni], a, 0, 0, 0);
          a = __builtin_amdgcn_mfma_f32_16x16x32_bf16(ah[mi], bl[ni], a, 0, 0, 0);
          a = __builtin_amdgcn_mfma_f32_16x16x32_bf16(ah[mi], bh[ni], a, 0, 0, 0);
          acc[mi][ni] = a;
        }
    }
    __syncthreads();
  }

#pragma unroll
  for (int mi = 0; mi < MI; mi++)
#pragma unroll
    for (int ni = 0; ni < NI; ni++) {
      int row = m0 + wm * (TM / 2) + mi * 16 + quad * 4;
      int col = n0 + wn * (TN / 2) + ni * 16 + l15;
#pragma unroll
      for (int r = 0; r < 4; r++)
        C[(size_t)(row + r) * ldc + col] = acc[mi][ni][r];
    }
}

// ---------------------------------------------------------------------------
// fp32 register-blocked GEMM — for the small GEMMs (2, 3).
// ---------------------------------------------------------------------------
template <int GM, int GN, int EPI>
__global__ __launch_bounds__(256) void gemm_tile(
    const float* __restrict__ A, int lda,
    const float* __restrict__ B, int ldb,
    const float* __restrict__ bias,
    float* __restrict__ C, int ldc,
    int N, int kslice_len, size_t slice_stride) {
  constexpr int BM = 64 * GM;
  constexpr int BN = 64 * GN;
  __shared__ float As[8][BM];
  __shared__ float Bs[8][BN];

  const int tid = threadIdx.x;
  const int tx = tid & 15;
  const int ty = tid >> 4;
  const int m0 = blockIdx.x * BM;
  const int n0 = blockIdx.y * BN;
  const int kbase = blockIdx.z * kslice_len;

  const int srow = tid >> 1;
  const int skk = (tid & 1) * 4;
  const bool a_act = (tid < BM * 2);
  const bool b_act = (tid < BN * 2);
  const bool b_in = b_act && (n0 + srow < N);

  const float* Aptr = A + (size_t)(m0 + srow) * lda + kbase + skk;
  const float* Bptr = B + (size_t)(n0 + srow) * ldb + kbase + skk;

  float4 pa = make_float4(0.f, 0.f, 0.f, 0.f);
  float4 pb = make_float4(0.f, 0.f, 0.f, 0.f);
  if (a_act) pa = *(const float4*)Aptr;
  if (b_in)  pb = *(const float4*)Bptr;

  float acc[GM][GN][4][4] = {};

  for (int kt = 0; kt < kslice_len; kt += 8) {
    __syncthreads();
    if (a_act) {
      As[skk + 0][srow] = pa.x; As[skk + 1][srow] = pa.y;
      As[skk + 2][srow] = pa.z; As[skk + 3][srow] = pa.w;
    }
    if (b_act) {
      Bs[skk + 0][srow] = pb.x; Bs[skk + 1][srow] = pb.y;
      Bs[skk + 2][srow] = pb.z; Bs[skk + 3][srow] = pb.w;
    }
    __syncthreads();
    if (kt + 8 < kslice_len) {
      if (a_act) pa = *(const float4*)(Aptr + kt + 8);
      if (b_in)  pb = *(const float4*)(Bptr + kt + 8);
    }
#pragma unroll
    for (int k = 0; k < 8; k++) {
      float a[GM][4], b[GN][4];
#pragma unroll
      for (int g = 0; g < GM; g++)
        *(float4*)&a[g][0] = *(const float4*)&As[k][g * 64 + ty * 4];
#pragma unroll
      for (int g = 0; g < GN; g++)
        *(float4*)&b[g][0] = *(const float4*)&Bs[k][g * 64 + tx * 4];
#pragma unroll
      for (int gm = 0; gm < GM; gm++)
#pragma unroll
        for (int i = 0; i < 4; i++)
#pragma unroll
          for (int gn = 0; gn < GN; gn++)
#pragma unroll
            for (int j = 0; j < 4; j++)
              acc[gm][gn][i][j] += a[gm][i] * b[gn][j];
    }
  }

  float* Cs = C + (size_t)blockIdx.z * slice_stride;
#pragma unroll
  for (int gm = 0; gm < GM; gm++) {
#pragma unroll
    for (int i = 0; i < 4; i++) {
      int m = m0 + gm * 64 + ty * 4 + i;
#pragma unroll
      for (int gn = 0; gn < GN; gn++) {
        int n = n0 + gn * 64 + tx * 4;
        if (n < N) {
          float4 v;
          v.x = acc[gm][gn][i][0]; v.y = acc[gm][gn][i][1];
          v.z = acc[gm][gn][i][2]; v.w = acc[gm][gn][i][3];
          if (EPI == 1) {
            v.x += bias[n + 0]; v.y += bias[n + 1];
            v.z += bias[n + 2]; v.w += bias[n + 3];
            v.x = (v.x > 20.f) ? v.x : log1pf(__expf(v.x));
            v.y = (v.y > 20.f) ? v.y : log1pf(__expf(v.y));
            v.z = (v.z > 20.f) ? v.z : log1pf(__expf(v.z));
            v.w = (v.w > 20.f) ? v.w : log1pf(__expf(v.w));
          }
          *(float4*)&Cs[(size_t)m * ldc + n] = v;
        }
      }
    }
  }
}

__global__ __launch_bounds__(256) void reduce4(
    const float* __restrict__ partials, float* __restrict__ outb, int n) {
  int i = blockIdx.x * 256 + threadIdx.x;
  if (i >= n) return;
  outb[i] = partials[i] + partials[i + n] + partials[i + 2 * n] + partials[i + 3 * n];
}

__global__ __launch_bounds__(256) void conv_silu(
    const float* __restrict__ xz, const float* __restrict__ cw,
    const float* __restrict__ cb, float* __restrict__ xs) {
  int idx = blockIdx.x * 256 + threadIdx.x;
  if (idx >= ROWS * DINNER) return;
  int d = idx & (DINNER - 1);
  int bt = idx >> 12;
  int t = bt & (SEQ - 1);
  float acc = cb[d];
#pragma unroll
  for (int k = 0; k < 4; k++) {
    int tt = t - 3 + k;
    if (tt >= 0) acc += cw[d * 4 + k] * xz[(size_t)(bt - 3 + k) * (2 * DINNER) + d];
  }
  xs[idx] = acc / (1.f + __expf(-acc));
}

// ---------------------------------------------------------------------------
// Chunked selective scan. Linear recurrence h_t = exp(delta_t*A)h + delta_t
// u_t B_t decomposed over NCHUNK chunks; chunk carry factor is
// exp(A * sum(delta)) (closed form), so pass1 stores only (h_partial, sumd).
//
// Pass 1: thread per (b,d,chunk); all 16 n-states in registers; zero init.
// Pass 2: thread per (b,d,n); 64-step prefix over chunks -> h0 per chunk.
// Pass 3: like pass1 seeded with h0; computes y, skip, gate; in-place write.
// ---------------------------------------------------------------------------
__global__ __launch_bounds__(256) void scan_pass1(
    const float* __restrict__ delta, const float* __restrict__ xs,
    const float* __restrict__ xdbl, const float* __restrict__ A_log,
    float* __restrict__ hpart, float* __restrict__ sumd) {
  int g = blockIdx.x * 256 + threadIdx.x;   // B*DINNER*NCHUNK = 524288
  int d = g & (DINNER - 1);
  int rest = g >> 12;
  int c = rest & (NCHUNK - 1);
  int b = rest >> 6;

  float Adn[16];
#pragma unroll
  for (int q = 0; q < 4; q++) {
    float4 a = *(const float4*)&A_log[d * 16 + q * 4];
    Adn[q * 4 + 0] = -__expf(a.x); Adn[q * 4 + 1] = -__expf(a.y);
    Adn[q * 4 + 2] = -__expf(a.z); Adn[q * 4 + 3] = -__expf(a.w);
  }

  float h[16] = {};
  float sd = 0.f;
  const size_t t0 = (size_t)b * SEQ + c * CLEN;
  const float* dp = delta + t0 * DINNER + d;
  const float* up = xs + t0 * DINNER + d;
  const float* xb = xdbl + t0 * XDBL_N + DTRANK;

  for (int i = 0; i < CLEN; i++) {
    float dt = dp[(size_t)i * DINNER];
    float u = up[(size_t)i * DINNER];
    sd += dt;
    float du = dt * u;
    float Bv[16];
#pragma unroll
    for (int q = 0; q < 4; q++)
      *(float4*)&Bv[q * 4] = *(const float4*)&xb[i * XDBL_N + q * 4];
#pragma unroll
    for (int n = 0; n < 16; n++)
      h[n] = __expf(dt * Adn[n]) * h[n] + du * Bv[n];
  }

  float* hp = hpart + ((size_t)(c * BATCH + b) * DINNER + d) * 16;
#pragma unroll
  for (int q = 0; q < 4; q++) *(float4*)&hp[q * 4] = *(const float4*)&h[q * 4];
  sumd[(size_t)(c * BATCH + b) * DINNER + d] = sd;
}

__global__ __launch_bounds__(256) void scan_pass2(
    const float* __restrict__ hpart, const float* __restrict__ sumd,
    const float* __restrict__ A_log, float* __restrict__ h0) {
  int g = blockIdx.x * 256 + threadIdx.x;   // B*DINNER*16 = 131072
  int n = g & 15;
  int d = (g >> 4) & (DINNER - 1);
  int b = g >> 16;

  float Adn = -__expf(A_log[d * 16 + n]);
  float h = 0.f;
  for (int c = 0; c < NCHUNK; c++) {
    size_t base = (size_t)(c * BATCH + b) * DINNER + d;
    h0[base * 16 + n] = h;
    h = __expf(Adn * sumd[base]) * h + hpart[base * 16 + n];
  }
}

__global__ __launch_bounds__(256) void scan_pass3(
    const float* __restrict__ xz, const float* __restrict__ xs,
    const float* __restrict__ xdbl, const float* __restrict__ A_log,
    const float* __restrict__ D_skip, const float* __restrict__ h0,
    float* __restrict__ delta_y) {
  int g = blockIdx.x * 256 + threadIdx.x;   // B*DINNER*NCHUNK
  int d = g & (DINNER - 1);
  int rest = g >> 12;
  int c = rest & (NCHUNK - 1);
  int b = rest >> 6;

  float Adn[16];
#pragma unroll
  for (int q = 0; q < 4; q++) {
    float4 a = *(const float4*)&A_log[d * 16 + q * 4];
    Adn[q * 4 + 0] = -__expf(a.x); Adn[q * 4 + 1] = -__expf(a.y);
    Adn[q * 4 + 2] = -__expf(a.z); Adn[q * 4 + 3] = -__expf(a.w);
  }
  float Dd = D_skip[d];

  float h[16];
  const float* hp = h0 + ((size_t)(c * BATCH + b) * DINNER + d) * 16;
#pragma unroll
  for (int q = 0; q < 4; q++) *(float4*)&h[q * 4] = *(const float4*)&hp[q * 4];

  const size_t t0 = (size_t)b * SEQ + c * CLEN;
  float* dl = delta_y + t0 * DINNER + d;
  const float* up = xs + t0 * DINNER + d;
  const float* zb = xz + t0 * (2 * DINNER) + DINNER + d;
  const float* xb = xdbl + t0 * XDBL_N + DTRANK;

  for (int i = 0; i < CLEN; i++) {
    float dt = dl[(size_t)i * DINNER];
    float u = up[(size_t)i * DINNER];
    float du = dt * u;
    float Bv[16], Cv[16];
#pragma unroll
    for (int q = 0; q < 4; q++) {
      *(float4*)&Bv[q * 4] = *(const float4*)&xb[i * XDBL_N + q * 4];
      *(float4*)&Cv[q * 4] = *(const float4*)&xb[i * XDBL_N + DSTATE + q * 4];
    }
    float y = 0.f;
#pragma unroll
    for (int n = 0; n < 16; n++) {
      h[n] = __expf(dt * Adn[n]) * h[n] + du * Bv[n];
      y += h[n] * Cv[n];
    }
    float z = zb[(size_t)i * (2 * DINNER)];
    float sz = z / (1.f + __expf(-z));
    dl[(size_t)i * DINNER] = (y + Dd * u) * sz;
  }
}

extern "C" void kernel_launch(void* const* d_in, const int* in_sizes, int n_in,
                              void* d_out, int out_size, void* d_ws, size_t ws_size,
                              hipStream_t stream) {
  const float* hidden = (const float*)d_in[0];
  const float* W_in   = (const float*)d_in[1];
  const float* conv_w = (const float*)d_in[2];
  const float* conv_b = (const float*)d_in[3];
  const float* W_x    = (const float*)d_in[4];
  const float* W_dt   = (const float*)d_in[5];
  const float* b_dt   = (const float*)d_in[6];
  const float* A_log  = (const float*)d_in[7];
  const float* D_skip = (const float*)d_in[8];
  const float* W_out  = (const float*)d_in[9];
  float* out = (float*)d_out;

  float* ws    = (float*)d_ws;
  float* xz    = ws;                                 // 16,777,216 f
  float* xs    = xz + (size_t)ROWS * 2 * DINNER;     //  8,388,608 f
  float* xdbl  = xs + (size_t)ROWS * DINNER;         //    327,680 f
  float* delta = xdbl + (size_t)ROWS * XDBL_N;       //  8,388,608 f
  float* partials = delta;                           // GEMM2 scratch (pre-GEMM3)
  ushort_t* Xh = (ushort_t*)(delta + (size_t)ROWS * DINNER);
  ushort_t* Xl = Xh + (size_t)ROWS * DINNER;
  ushort_t* Wh = Xl + (size_t)ROWS * DINNER;
  ushort_t* Wl = Wh + (size_t)2 * DINNER * DMODEL;
  // scan scratch aliases regions that are dead between GEMM3 and GEMM4 splits:
  float* hpart = (float*)Wh;   // 8,388,608 f = 33.55 MB (== Wh region size)
  float* h0    = (float*)Wl;   // 8,388,608 f
  float* sumd  = (float*)Xh;   // 524,288 f (Xh region = 16.8 MB)

  dim3 blk(256);

  split_bf16<<<(ROWS * DMODEL / 4 + 255) / 256, blk, 0, stream>>>(
      hidden, Xh, Xl, ROWS * DMODEL / 4);
  split_bf16<<<(2 * DINNER * DMODEL / 4 + 255) / 256, blk, 0, stream>>>(
      W_in, Wh, Wl, 2 * DINNER * DMODEL / 4);

  // GEMM1 (MFMA): xz = hidden @ W_in^T : M=2048, N=8192, K=2048
  gemm_mfma<128, 128><<<dim3(ROWS / 128, 2 * DINNER / 128), blk, 0, stream>>>(
      Xh, Xl, Wh, Wl, xz, 2 * DINNER, DMODEL);

  conv_silu<<<(ROWS * DINNER + 255) / 256, blk, 0, stream>>>(xz, conv_w, conv_b, xs);

  // GEMM2 (fp32): x_dbl = xs @ W_x^T : M=2048, N=160, K=4096, split-K=4
  gemm_tile<1, 1, 0><<<dim3(ROWS / 64, 3, 4), blk, 0, stream>>>(
      xs, DINNER, W_x, DINNER, nullptr, partials, XDBL_N,
      XDBL_N, DINNER / 4, (size_t)ROWS * XDBL_N);
  reduce4<<<(ROWS * XDBL_N + 255) / 256, blk, 0, stream>>>(
      partials, xdbl, ROWS * XDBL_N);

  // GEMM3 (fp32): delta = softplus(x_dbl[:, :128] @ W_dt^T + b_dt)
  gemm_tile<2, 2, 1><<<dim3(ROWS / 128, DINNER / 128, 1), blk, 0, stream>>>(
      xdbl, XDBL_N, W_dt, DTRANK, b_dt, delta, DINNER,
      DINNER, DTRANK, 0);

  // chunked scan (replaces sequential scan_kernel)
  scan_pass1<<<(BATCH * DINNER * NCHUNK) / 256, blk, 0, stream>>>(
      delta, xs, xdbl, A_log, hpart, sumd);
  scan_pass2<<<(BATCH * DINNER * DSTATE) / 256, blk, 0, stream>>>(
      hpart, sumd, A_log, h0);
  scan_pass3<<<(BATCH * DINNER * NCHUNK) / 256, blk, 0, stream>>>(
      xz, xs, xdbl, A_log, D_skip, h0, delta);

  split_bf16<<<(ROWS * DINNER / 4 + 255) / 256, blk, 0, stream>>>(
      delta, Xh, Xl, ROWS * DINNER / 4);
  split_bf16<<<(DMODEL * DINNER / 4 + 255) / 256, blk, 0, stream>>>(
      W_out, Wh, Wl, DMODEL * DINNER / 4);

  // GEMM4 (MFMA): out = gated @ W_out^T : M=2048, N=2048, K=4096
  gemm_mfma<128, 64><<<dim3(ROWS / 128, DMODEL / 64), blk, 0, stream>>>(
      Xh, Xl, Wh, Wl, out, DMODEL, DINNER);
}

// Round 6
// 502.626 us; speedup vs baseline: 7.5182x; 1.4947x over previous
//
#include <hip/hip_runtime.h>
#include <hip/hip_bf16.h>

// Mamba mixer forward. Round 6: round-5 design (single-bf16 MFMA for all
// GEMMs, fused casts, chunked scan) with the workspace-layout bug fixed:
// Hb was offset by hph + ROWS*DINNER*4 *floats* (4x overrun, 334 MB > ws)
// -> now hph + hph_size (233 MB total, within the proven 236 MB footprint).
// B=2, L=1024, D_MODEL=2048, D_INNER=4096, D_STATE=16, D_CONV=4, DT_RANK=128.

#define BATCH 2
#define SEQ 1024
#define DMODEL 2048
#define DINNER 4096
#define DSTATE 16
#define DTRANK 128
#define ROWS (BATCH * SEQ)            // 2048
#define XDBL_N (DTRANK + 2 * DSTATE)  // 160
#define NCHUNK 64
#define CLEN (SEQ / NCHUNK)           // 16
#define WXPAD 192                     // W_x rows padded 160 -> 192

typedef unsigned short ushort_t;
typedef __attribute__((ext_vector_type(8))) short short8;
typedef __attribute__((ext_vector_type(4))) float f32x4;

__device__ __forceinline__ ushort_t bf16_rne(float f) {
  unsigned u = __float_as_uint(f);
  return (ushort_t)((u + 0x7FFFu + ((u >> 16) & 1u)) >> 16);
}

// fp32 -> bf16 cast, float4-vectorized. n4 = n/4.
__global__ __launch_bounds__(256) void cast_bf16(
    const float* __restrict__ x, ushort_t* __restrict__ o, int n4) {
  int i = blockIdx.x * 256 + threadIdx.x;
  if (i >= n4) return;
  float4 v = ((const float4*)x)[i];
  ushort4 h;
  h.x = bf16_rne(v.x); h.y = bf16_rne(v.y);
  h.z = bf16_rne(v.z); h.w = bf16_rne(v.w);
  ((ushort4*)o)[i] = h;
}

// W_x (160 x 4096) -> bf16 padded to 192 rows (zeros).
__global__ __launch_bounds__(256) void cast_wx(
    const float* __restrict__ wx, ushort_t* __restrict__ o) {
  int i = blockIdx.x * 256 + threadIdx.x;   // over 192*1024 float4s
  if (i >= WXPAD * (DINNER / 4)) return;
  int row = i >> 10;                         // /1024
  ushort4 h = {0, 0, 0, 0};
  if (row < XDBL_N) {
    float4 v = ((const float4*)wx)[i];
    h.x = bf16_rne(v.x); h.y = bf16_rne(v.y);
    h.z = bf16_rne(v.z); h.w = bf16_rne(v.w);
  }
  ((ushort4*)o)[i] = h;
}

// ---------------------------------------------------------------------------
// Single-bf16 MFMA GEMM: C = X @ W^T, fp32 out. X: M x lda, W: N x ldb (bf16).
// TM x TN tile, 256 thr (4 waves, 2x2). BK=64. Staging via global_load_lds
// width-16, XOR-swizzled LDS (slot16(m,c) = m*8 + (c ^ (m&7))) -> conflict-
// free ds_read_b128. EPI 1: softplus(acc + bias[col]). SK: split-K over
// blockIdx.z (slice length kslice, output offset z*sstride).
// M % TM == 0, N % TN == 0, kslice % 64 == 0 at all call sites.
// ---------------------------------------------------------------------------
template <int TM, int TN, int EPI, bool SK>
__global__ __launch_bounds__(256, 2) void gemm_bf16(
    const ushort_t* __restrict__ X, int lda,
    const ushort_t* __restrict__ W, int ldb,
    const float* __restrict__ bias,
    float* __restrict__ C, int ldc, int kslice, size_t sstride) {
  constexpr int MI = TM / 32;       // 16-row MFMA tiles per wave (m)
  constexpr int NI = TN / 32;       // 16-col MFMA tiles per wave (n)
  constexpr int G = (TM + TN) / 32; // staging instrs per wave (8 rows each)
  __shared__ __attribute__((aligned(16))) ushort_t lds[(TM + TN) * 64];

  const int tid = threadIdx.x;
  const int lane = tid & 63;
  const int w = tid >> 6;
  const int wm = w & 1, wn = w >> 1;
  const int m0 = blockIdx.x * TM;
  const int n0 = blockIdx.y * TN;
  const int kbase = SK ? blockIdx.z * kslice : 0;

  const int lrow = lane >> 3;            // 0..7
  const int csw = (lane & 7) ^ lrow;     // source chunk for swizzled store
  const int quad = lane >> 4;
  const int l15 = lane & 15;
  const int x0 = quad ^ (lane & 7);
  const int baseA = (wm * (TM / 2) + l15) * 64;
  const int baseB = (TM + wn * (TN / 2) + l15) * 64;

  f32x4 acc[MI][NI] = {};

  for (int kt = 0; kt < kslice; kt += 64) {
#pragma unroll
    for (int j = 0; j < G; j++) {
      const int r0 = (w * G + j) * 8;
      const int row = r0 + lrow;
      const ushort_t* src = (r0 < TM)
          ? X + (size_t)(m0 + row) * lda + kbase + kt + csw * 8
          : W + (size_t)(n0 + row - TM) * ldb + kbase + kt + csw * 8;
      __builtin_amdgcn_global_load_lds(
          (const __attribute__((address_space(1))) unsigned int*)src,
          (__attribute__((address_space(3))) unsigned int*)&lds[r0 * 64],
          16, 0, 0);
    }
    __syncthreads();

#pragma unroll
    for (int ks = 0; ks < 2; ks++) {
      const int xo = (x0 ^ (ks * 4)) * 8;
      short8 a[MI], b[NI];
#pragma unroll
      for (int mi = 0; mi < MI; mi++)
        a[mi] = *(const short8*)&lds[baseA + mi * 1024 + xo];
#pragma unroll
      for (int ni = 0; ni < NI; ni++)
        b[ni] = *(const short8*)&lds[baseB + ni * 1024 + xo];
#pragma unroll
      for (int mi = 0; mi < MI; mi++)
#pragma unroll
        for (int ni = 0; ni < NI; ni++)
          acc[mi][ni] = __builtin_amdgcn_mfma_f32_16x16x32_bf16(
              a[mi], b[ni], acc[mi][ni], 0, 0, 0);
    }
    __syncthreads();
  }

  float* Cs = SK ? (C + (size_t)blockIdx.z * sstride) : C;
  // C/D layout: col = lane&15, row = quad*4 + reg
#pragma unroll
  for (int mi = 0; mi < MI; mi++)
#pragma unroll
    for (int ni = 0; ni < NI; ni++) {
      int row = m0 + wm * (TM / 2) + mi * 16 + quad * 4;
      int col = n0 + wn * (TN / 2) + ni * 16 + l15;
#pragma unroll
      for (int r = 0; r < 4; r++) {
        float v = acc[mi][ni][r];
        if (EPI == 1) {
          v += bias[col];
          v = (v > 20.f) ? v : log1pf(__expf(v));
        }
        Cs[(size_t)(row + r) * ldc + col] = v;
      }
    }
}

// Sum 8 split-K partial buffers (2048 x 192 each) -> xdbl fp32 (cols<160)
// and bf16 dt slice (cols<128).
__global__ __launch_bounds__(192) void reduce8(
    const float* __restrict__ partials, float* __restrict__ xdbl,
    ushort_t* __restrict__ dtb) {
  int m = blockIdx.x;
  int c = threadIdx.x;
  if (c >= XDBL_N) return;
  float s = 0.f;
#pragma unroll
  for (int z = 0; z < 8; z++)
    s += partials[(size_t)z * ROWS * WXPAD + (size_t)m * WXPAD + c];
  xdbl[(size_t)m * XDBL_N + c] = s;
  if (c < DTRANK) dtb[(size_t)m * DTRANK + c] = bf16_rne(s);
}

// Causal depthwise conv (D_CONV=4) + SiLU; writes fp32 xs and bf16 xs_b.
__global__ __launch_bounds__(256) void conv_silu(
    const float* __restrict__ xz, const float* __restrict__ cw,
    const float* __restrict__ cb, float* __restrict__ xs,
    ushort_t* __restrict__ xsb) {
  int idx = blockIdx.x * 256 + threadIdx.x;
  if (idx >= ROWS * DINNER) return;
  int d = idx & (DINNER - 1);
  int bt = idx >> 12;
  int t = bt & (SEQ - 1);
  float acc = cb[d];
#pragma unroll
  for (int k = 0; k < 4; k++) {
    int tt = t - 3 + k;
    if (tt >= 0) acc += cw[d * 4 + k] * xz[(size_t)(bt - 3 + k) * (2 * DINNER) + d];
  }
  float s = acc / (1.f + __expf(-acc));
  xs[idx] = s;
  xsb[idx] = bf16_rne(s);
}

// ---------------------------------------------------------------------------
// Chunked selective scan. Pass2 runs in place on hph (hpart in, h0 out).
// Pass3 emits gated output directly as bf16.
// ---------------------------------------------------------------------------
__global__ __launch_bounds__(256) void scan_pass1(
    const float* __restrict__ delta, const float* __restrict__ xs,
    const float* __restrict__ xdbl, const float* __restrict__ A_log,
    float* __restrict__ hpart, float* __restrict__ sumd) {
  int g = blockIdx.x * 256 + threadIdx.x;   // B*DINNER*NCHUNK = 524288
  int d = g & (DINNER - 1);
  int rest = g >> 12;
  int c = rest & (NCHUNK - 1);
  int b = rest >> 6;

  float Adn[16];
#pragma unroll
  for (int q = 0; q < 4; q++) {
    float4 a = *(const float4*)&A_log[d * 16 + q * 4];
    Adn[q * 4 + 0] = -__expf(a.x); Adn[q * 4 + 1] = -__expf(a.y);
    Adn[q * 4 + 2] = -__expf(a.z); Adn[q * 4 + 3] = -__expf(a.w);
  }

  float h[16] = {};
  float sd = 0.f;
  const size_t t0 = (size_t)b * SEQ + c * CLEN;
  const float* dp = delta + t0 * DINNER + d;
  const float* up = xs + t0 * DINNER + d;
  const float* xb = xdbl + t0 * XDBL_N + DTRANK;

  for (int i = 0; i < CLEN; i++) {
    float dt = dp[(size_t)i * DINNER];
    float u = up[(size_t)i * DINNER];
    sd += dt;
    float du = dt * u;
    float Bv[16];
#pragma unroll
    for (int q = 0; q < 4; q++)
      *(float4*)&Bv[q * 4] = *(const float4*)&xb[i * XDBL_N + q * 4];
#pragma unroll
    for (int n = 0; n < 16; n++)
      h[n] = __expf(dt * Adn[n]) * h[n] + du * Bv[n];
  }

  float* hp = hpart + ((size_t)(c * BATCH + b) * DINNER + d) * 16;
#pragma unroll
  for (int q = 0; q < 4; q++) *(float4*)&hp[q * 4] = *(const float4*)&h[q * 4];
  sumd[(size_t)(c * BATCH + b) * DINNER + d] = sd;
}

__global__ __launch_bounds__(256) void scan_pass2(
    float* __restrict__ hph, const float* __restrict__ sumd,
    const float* __restrict__ A_log) {
  int g = blockIdx.x * 256 + threadIdx.x;   // B*DINNER*16 = 131072
  int n = g & 15;
  int d = (g >> 4) & (DINNER - 1);
  int b = g >> 16;

  float Adn = -__expf(A_log[d * 16 + n]);
  float h = 0.f;
  for (int c = 0; c < NCHUNK; c++) {
    size_t base = (size_t)(c * BATCH + b) * DINNER + d;
    float part = hph[base * 16 + n];
    hph[base * 16 + n] = h;                    // h0 for chunk c (in place)
    h = __expf(Adn * sumd[base]) * h + part;
  }
}

__global__ __launch_bounds__(256) void scan_pass3(
    const float* __restrict__ xz, const float* __restrict__ xs,
    const float* __restrict__ xdbl, const float* __restrict__ A_log,
    const float* __restrict__ D_skip, const float* __restrict__ h0,
    const float* __restrict__ delta, ushort_t* __restrict__ gated) {
  int g = blockIdx.x * 256 + threadIdx.x;   // B*DINNER*NCHUNK
  int d = g & (DINNER - 1);
  int rest = g >> 12;
  int c = rest & (NCHUNK - 1);
  int b = rest >> 6;

  float Adn[16];
#pragma unroll
  for (int q = 0; q < 4; q++) {
    float4 a = *(const float4*)&A_log[d * 16 + q * 4];
    Adn[q * 4 + 0] = -__expf(a.x); Adn[q * 4 + 1] = -__expf(a.y);
    Adn[q * 4 + 2] = -__expf(a.z); Adn[q * 4 + 3] = -__expf(a.w);
  }
  float Dd = D_skip[d];

  float h[16];
  const float* hp = h0 + ((size_t)(c * BATCH + b) * DINNER + d) * 16;
#pragma unroll
  for (int q = 0; q < 4; q++) *(float4*)&h[q * 4] = *(const float4*)&hp[q * 4];

  const size_t t0 = (size_t)b * SEQ + c * CLEN;
  const float* dl = delta + t0 * DINNER + d;
  const float* up = xs + t0 * DINNER + d;
  const float* zb = xz + t0 * (2 * DINNER) + DINNER + d;
  const float* xb = xdbl + t0 * XDBL_N + DTRANK;
  ushort_t* gp = gated + t0 * DINNER + d;

  for (int i = 0; i < CLEN; i++) {
    float dt = dl[(size_t)i * DINNER];
    float u = up[(size_t)i * DINNER];
    float du = dt * u;
    float Bv[16], Cv[16];
#pragma unroll
    for (int q = 0; q < 4; q++) {
      *(float4*)&Bv[q * 4] = *(const float4*)&xb[i * XDBL_N + q * 4];
      *(float4*)&Cv[q * 4] = *(const float4*)&xb[i * XDBL_N + DSTATE + q * 4];
    }
    float y = 0.f;
#pragma unroll
    for (int n = 0; n < 16; n++) {
      h[n] = __expf(dt * Adn[n]) * h[n] + du * Bv[n];
      y += h[n] * Cv[n];
    }
    float z = zb[(size_t)i * (2 * DINNER)];
    float sz = z / (1.f + __expf(-z));
    gp[(size_t)i * DINNER] = bf16_rne((y + Dd * u) * sz);
  }
}

extern "C" void kernel_launch(void* const* d_in, const int* in_sizes, int n_in,
                              void* d_out, int out_size, void* d_ws, size_t ws_size,
                              hipStream_t stream) {
  const float* hidden = (const float*)d_in[0];
  const float* W_in   = (const float*)d_in[1];
  const float* conv_w = (const float*)d_in[2];
  const float* conv_b = (const float*)d_in[3];
  const float* W_x    = (const float*)d_in[4];
  const float* W_dt   = (const float*)d_in[5];
  const float* b_dt   = (const float*)d_in[6];
  const float* A_log  = (const float*)d_in[7];
  const float* D_skip = (const float*)d_in[8];
  const float* W_out  = (const float*)d_in[9];
  float* out = (float*)d_out;

  // ---- workspace layout (fp32 section then bf16 section), total ~233 MB ----
  float* ws    = (float*)d_ws;
  float* xz    = ws;                               // 16,777,216 f
  float* xs    = xz + (size_t)ROWS * 2 * DINNER;   //  8,388,608 f
  float* xdbl  = xs + (size_t)ROWS * DINNER;       //    327,680 f
  float* delta = xdbl + (size_t)ROWS * XDBL_N;     //  8,388,608 f
  float* sumd  = delta + (size_t)ROWS * DINNER;    //    524,288 f
  float* hph   = sumd + (size_t)BATCH * DINNER * NCHUNK;  // 8,388,608 f
  // FIX (round-5 crash): advance by hph's SIZE IN FLOATS (B*Di*NCHUNK*16
  // = 8,388,608), not ROWS*DINNER*4 (which was 4x too far -> ws overrun).
  ushort_t* Hb   = (ushort_t*)(hph + (size_t)BATCH * DINNER * NCHUNK * DSTATE);
  ushort_t* Wb1  = Hb + (size_t)ROWS * DMODEL;         //  4,194,304 us Hb
  ushort_t* Wxb  = Wb1 + (size_t)2 * DINNER * DMODEL;  // 16,777,216 us Wb1
  ushort_t* Wdtb = Wxb + (size_t)WXPAD * DINNER;       //    786,432 us Wxb
  ushort_t* xsb  = Wdtb + (size_t)DINNER * DTRANK;     //    524,288 us Wdtb
  ushort_t* dtb  = xsb + (size_t)ROWS * DINNER;        //  8,388,608 us xsb
  // (dtb: 262,144 us) -> end of ws at ~233.0 MB
  // aliases into Wb1 (dead after GEMM1):
  float* partials = (float*)Wb1;                    // 8*2048*192 f = 12.6 MB
  ushort_t* Woutb = Wb1;                            // 2048*4096 us = 16.8 MB
  ushort_t* gatedb = Wb1 + (size_t)DMODEL * DINNER; // 16.8 MB (2nd half)

  dim3 blk(256);

  // casts for GEMM1
  cast_bf16<<<(ROWS * DMODEL / 4 + 255) / 256, blk, 0, stream>>>(
      hidden, Hb, ROWS * DMODEL / 4);
  cast_bf16<<<(2 * DINNER * DMODEL / 4 + 255) / 256, blk, 0, stream>>>(
      W_in, Wb1, 2 * DINNER * DMODEL / 4);

  // GEMM1: xz = hidden @ W_in^T : M=2048, N=8192, K=2048. 128x256 tiles.
  gemm_bf16<128, 256, 0, false><<<dim3(16, 32), blk, 0, stream>>>(
      Hb, DMODEL, Wb1, DMODEL, nullptr, xz, 2 * DINNER, DMODEL, 0);

  // conv + silu -> xs (fp32) + xsb (bf16)
  conv_silu<<<(ROWS * DINNER + 255) / 256, blk, 0, stream>>>(
      xz, conv_w, conv_b, xs, xsb);

  // casts for GEMM2/GEMM3 weights
  cast_wx<<<(WXPAD * DINNER / 4 + 255) / 256, blk, 0, stream>>>(W_x, Wxb);
  cast_bf16<<<(DINNER * DTRANK / 4 + 255) / 256, blk, 0, stream>>>(
      W_dt, Wdtb, DINNER * DTRANK / 4);

  // GEMM2: x_dbl = xs @ W_x^T : M=2048, N=192(pad), K=4096, split-K=8
  gemm_bf16<128, 64, 0, true><<<dim3(16, 3, 8), blk, 0, stream>>>(
      xsb, DINNER, Wxb, DINNER, nullptr, partials, WXPAD, DINNER / 8,
      (size_t)ROWS * WXPAD);
  reduce8<<<ROWS, dim3(WXPAD), 0, stream>>>(partials, xdbl, dtb);

  // GEMM3: delta = softplus(dt @ W_dt^T + b_dt) : M=2048, N=4096, K=128
  gemm_bf16<128, 128, 1, false><<<dim3(16, 32), blk, 0, stream>>>(
      dtb, DTRANK, Wdtb, DTRANK, b_dt, delta, DINNER, DTRANK, 0);

  // chunked scan; pass3 emits gated bf16
  scan_pass1<<<(BATCH * DINNER * NCHUNK) / 256, blk, 0, stream>>>(
      delta, xs, xdbl, A_log, hph, sumd);
  scan_pass2<<<(BATCH * DINNER * DSTATE) / 256, blk, 0, stream>>>(
      hph, sumd, A_log);
  scan_pass3<<<(BATCH * DINNER * NCHUNK) / 256, blk, 0, stream>>>(
      xz, xs, xdbl, A_log, D_skip, hph, delta, gatedb);

  // cast W_out (overwrites partials region — dead since reduce8)
  cast_bf16<<<(DMODEL * DINNER / 4 + 255) / 256, blk, 0, stream>>>(
      W_out, Woutb, DMODEL * DINNER / 4);

  // GEMM4: out = gated @ W_out^T : M=2048, N=2048, K=4096. 128x128 tiles.
  gemm_bf16<128, 128, 0, false><<<dim3(16, 16), blk, 0, stream>>>(
      gatedb, DINNER, Woutb, DINNER, nullptr, out, DMODEL, DINNER, 0);
}